// Round 8
// baseline (326.649 us; speedup 1.0000x reference)
//
#include <hip/hip_runtime.h>
#include <hip/hip_bf16.h>

// ---------------------------------------------------------------------------
// T5 MHA: B=2, S=2048, D_FF=1024, H=16, DK=64, INNER=1024
// Precision: q carried hi+lo (2-chain QK vs k_hi); W's split for projections.
// Attn v6: 512-thr blocks, 8 waves; IN-BLOCK KV-SPLIT: waves 0-3 kv[0,1024),
//   waves 4-7 kv[1024,2048), each wave q=32 (halves LDS reads per MFMA vs v5).
//   Online-softmax partials merged in LDS at the end. exp2 path (Q pre-scaled
//   by log2e), v_cvt_pk_bf16_f32 P-pack, defer-max (THR=8), setprio.
// ---------------------------------------------------------------------------

typedef __attribute__((ext_vector_type(8))) short short8_t;   // 8 bf16 (4 VGPR)
typedef __attribute__((ext_vector_type(4))) short short4_t;
typedef __attribute__((ext_vector_type(4))) float f32x4_t;

#define SEQ 2048
#define HEADS 16
#define DK 64
#define DFF 1024
#define LOG2E 1.44269504088896340736f

__device__ __forceinline__ unsigned short f32_to_bf16(float f) {
  unsigned int u = __float_as_uint(f);
  u += 0x7FFFu + ((u >> 16) & 1u);   // round-to-nearest-even
  return (unsigned short)(u >> 16);
}
__device__ __forceinline__ float bf16_to_f32(unsigned short h) {
  return __uint_as_float(((unsigned int)h) << 16);
}
__device__ __forceinline__ unsigned int cvt_pk_bf16(float a, float b) {
  unsigned int r;
  asm("v_cvt_pk_bf16_f32 %0, %1, %2" : "=v"(r) : "v"(a), "v"(b));
  return r;
}

__device__ __forceinline__ void gload_lds16(const void* g, void* l) {
  __builtin_amdgcn_global_load_lds(
      (__attribute__((address_space(1))) void*)(g),
      (__attribute__((address_space(3))) void*)(l), 16, 0, 0);
}

// ---------------------------------------------------------------------------
// cvt_x: q/k/v fp32 -> bf16, one dispatch
// ---------------------------------------------------------------------------
__global__ void cvt_x_kernel(const float* __restrict__ q,
                             const float* __restrict__ k,
                             const float* __restrict__ v,
                             short* __restrict__ dst, int n) {
  const float* src = (blockIdx.y == 0) ? q : (blockIdx.y == 1) ? k : v;
  short* out = dst + (size_t)blockIdx.y * n;
  int i = (blockIdx.x * 256 + threadIdx.x) * 4;
  if (i >= n) return;
  float4 f = *(const float4*)(src + i);
  short4_t s;
  s[0] = (short)f32_to_bf16(f.x);
  s[1] = (short)f32_to_bf16(f.y);
  s[2] = (short)f32_to_bf16(f.z);
  s[3] = (short)f32_to_bf16(f.w);
  *(short4_t*)(out + i) = s;
}

// ---------------------------------------------------------------------------
// cvt_w: y<3 -> split W[y] into hi+lo pair; y==3 -> plain Wo
// ---------------------------------------------------------------------------
__global__ void cvt_w_kernel(const float* __restrict__ Wq,
                             const float* __restrict__ Wk,
                             const float* __restrict__ Wv,
                             const float* __restrict__ Wo,
                             short* __restrict__ wbase, int n) {
  int y = blockIdx.y;
  const float* src = (y == 0) ? Wq : (y == 1) ? Wk : (y == 2) ? Wv : Wo;
  int i = (blockIdx.x * 256 + threadIdx.x) * 4;
  if (i >= n) return;
  float4 f = *(const float4*)(src + i);
  float ff[4] = {f.x, f.y, f.z, f.w};
  if (y < 3) {
    short* hi = wbase + (size_t)(2 * y) * n;
    short* lo = wbase + (size_t)(2 * y + 1) * n;
    short4_t h, l;
#pragma unroll
    for (int j = 0; j < 4; ++j) {
      unsigned short hh = f32_to_bf16(ff[j]);
      h[j] = (short)hh;
      l[j] = (short)f32_to_bf16(ff[j] - bf16_to_f32(hh));
    }
    *(short4_t*)(hi + i) = h;
    *(short4_t*)(lo + i) = l;
  } else {
    short* out = wbase + (size_t)6 * n;
    short4_t s;
#pragma unroll
    for (int j = 0; j < 4; ++j) s[j] = (short)f32_to_bf16(ff[j]);
    *(short4_t*)(out + i) = s;
  }
}

// ---------------------------------------------------------------------------
// Projection GEMM: C[M,1024] = A[M,K] @ (Bh+Bl)[1024,K]^T, 2 MFMA chains.
// Tile 128M x 64N. EPI 0: Q hi+lo head-split, PRE-SCALED by log2e.
// EPI 1: K hi head-split. EPI 2: V hi TRANSPOSED [B,H,64,S].
// ---------------------------------------------------------------------------
template <int EPI>
__global__ __launch_bounds__(256, 2) void gemm_proj(
    const short* __restrict__ A, const short* __restrict__ Bh,
    const short* __restrict__ Bl, short* __restrict__ Ohi,
    short* __restrict__ Olo, int M, int K) {
  __shared__ short As[128 * 32];
  __shared__ short Bsh[64 * 32];
  __shared__ short Bsl[64 * 32];

  const int tid = threadIdx.x;
  const int w = tid >> 6, l = tid & 63, g = l >> 4, c = l & 15;
  const int wr = w >> 1, wc = w & 1;
  const int m0 = blockIdx.y * 128, n0 = blockIdx.x * 64;

  f32x4_t acc[4][2] = {};

  for (int k0 = 0; k0 < K; k0 += 32) {
#pragma unroll
    for (int j = 0; j < 2; ++j) {
      int e = (w * 2 + j) * 512 + l * 8;
      int r = e >> 5, cc = e & 31;
      gload_lds16(A + (size_t)(m0 + r) * K + k0 + cc, &As[(w * 2 + j) * 512]);
    }
    {
      int e = w * 512 + l * 8;
      int r = e >> 5, cc = e & 31;
      gload_lds16(Bh + (size_t)(n0 + r) * K + k0 + cc, &Bsh[w * 512]);
      gload_lds16(Bl + (size_t)(n0 + r) * K + k0 + cc, &Bsl[w * 512]);
    }
    __syncthreads();

    short8_t a[4], bh[2], bl[2];
#pragma unroll
    for (int mi = 0; mi < 4; ++mi)
      a[mi] = *(const short8_t*)(&As[(wr * 64 + mi * 16 + c) * 32 + g * 8]);
#pragma unroll
    for (int ni = 0; ni < 2; ++ni) {
      bh[ni] = *(const short8_t*)(&Bsh[(wc * 32 + ni * 16 + c) * 32 + g * 8]);
      bl[ni] = *(const short8_t*)(&Bsl[(wc * 32 + ni * 16 + c) * 32 + g * 8]);
    }
#pragma unroll
    for (int mi = 0; mi < 4; ++mi)
#pragma unroll
      for (int ni = 0; ni < 2; ++ni) {
        acc[mi][ni] = __builtin_amdgcn_mfma_f32_16x16x32_bf16(
            a[mi], bh[ni], acc[mi][ni], 0, 0, 0);
        acc[mi][ni] = __builtin_amdgcn_mfma_f32_16x16x32_bf16(
            a[mi], bl[ni], acc[mi][ni], 0, 0, 0);
      }
    __syncthreads();
  }

#pragma unroll
  for (int mi = 0; mi < 4; ++mi) {
#pragma unroll
    for (int ni = 0; ni < 2; ++ni) {
      int col = n0 + wc * 32 + ni * 16 + c;
      int hh = col >> 6, dd = col & 63;
      if (EPI == 2) {
        int row0 = m0 + wr * 64 + mi * 16 + g * 4;
        int bb = row0 >> 11, ss0 = row0 & 2047;
        short4_t s4;
#pragma unroll
        for (int j = 0; j < 4; ++j) s4[j] = (short)f32_to_bf16(acc[mi][ni][j]);
        *(short4_t*)(&Ohi[(((size_t)bb * HEADS + hh) * DK + dd) * SEQ + ss0]) = s4;
      } else {
#pragma unroll
        for (int j = 0; j < 4; ++j) {
          int row = m0 + wr * 64 + mi * 16 + g * 4 + j;
          int bb = row >> 11, ss = row & 2047;
          size_t idx = (((size_t)bb * HEADS + hh) * SEQ + ss) * DK + dd;
          float x = acc[mi][ni][j];
          if (EPI == 0) x *= LOG2E;   // fold log2e into Q for exp2 softmax
          unsigned short xh = f32_to_bf16(x);
          Ohi[idx] = (short)xh;
          if (EPI == 0)
            Olo[idx] = (short)f32_to_bf16(x - bf16_to_f32(xh));
        }
      }
    }
  }
}

// ---------------------------------------------------------------------------
// Output GEMM: O[M,1024] fp32 = A[M,K] @ Bw[1024,K]^T, plain bf16, 1 chain.
// ---------------------------------------------------------------------------
__global__ __launch_bounds__(256, 2) void gemm_out(
    const short* __restrict__ A, const short* __restrict__ Bw,
    float* __restrict__ O, int M, int K) {
  __shared__ short As[128 * 32];
  __shared__ short Bs[64 * 32];

  const int tid = threadIdx.x;
  const int w = tid >> 6, l = tid & 63, g = l >> 4, c = l & 15;
  const int wr = w >> 1, wc = w & 1;
  const int m0 = blockIdx.y * 128, n0 = blockIdx.x * 64;

  f32x4_t acc[4][2] = {};

  for (int k0 = 0; k0 < K; k0 += 32) {
#pragma unroll
    for (int j = 0; j < 2; ++j) {
      int e = (w * 2 + j) * 512 + l * 8;
      int r = e >> 5, cc = e & 31;
      gload_lds16(A + (size_t)(m0 + r) * K + k0 + cc, &As[(w * 2 + j) * 512]);
    }
    {
      int e = w * 512 + l * 8;
      int r = e >> 5, cc = e & 31;
      gload_lds16(Bw + (size_t)(n0 + r) * K + k0 + cc, &Bs[w * 512]);
    }
    __syncthreads();

    short8_t a[4], b[2];
#pragma unroll
    for (int mi = 0; mi < 4; ++mi)
      a[mi] = *(const short8_t*)(&As[(wr * 64 + mi * 16 + c) * 32 + g * 8]);
#pragma unroll
    for (int ni = 0; ni < 2; ++ni)
      b[ni] = *(const short8_t*)(&Bs[(wc * 32 + ni * 16 + c) * 32 + g * 8]);
#pragma unroll
    for (int mi = 0; mi < 4; ++mi)
#pragma unroll
      for (int ni = 0; ni < 2; ++ni)
        acc[mi][ni] = __builtin_amdgcn_mfma_f32_16x16x32_bf16(
            a[mi], b[ni], acc[mi][ni], 0, 0, 0);
    __syncthreads();
  }

#pragma unroll
  for (int mi = 0; mi < 4; ++mi)
#pragma unroll
    for (int ni = 0; ni < 2; ++ni) {
      int col = n0 + wc * 32 + ni * 16 + c;
#pragma unroll
      for (int j = 0; j < 4; ++j) {
        int row = m0 + wr * 64 + mi * 16 + g * 4 + j;
        O[(size_t)row * DFF + col] = acc[mi][ni][j];
      }
    }
}

// ---------------------------------------------------------------------------
// Flash attention v6. Grid (B*H, S/128), 512 thr = 8 waves.
// Wave w: kv-group grp=w>>2 (kv half), q-subtile pw=w&3 (32 q-rows).
// Each wave: q=32 (mi=0,1), kv chunks of 64, 16 chunks per group.
// S^T: mfma(A=K_hi rows kv, B=Q rows q). PV: O^T = mfma(A=V^T, B=P).
// End: group-B waves dump (o,m,l) to LDS; group-A merges, normalizes, stores.
// All scores/maxes in log2 units (Q pre-scaled by log2e; mask via fmaf).
// ---------------------------------------------------------------------------
__global__ __launch_bounds__(512, 4) void attn_kernel(
    const short* __restrict__ qhh, const short* __restrict__ qhl,
    const short* __restrict__ khh, const short* __restrict__ vt,
    const float* __restrict__ mask, short* __restrict__ ctx) {
  const int bh = blockIdx.x;
  const int b = bh >> 4;
  const int h = bh & 15;
  const int qt = blockIdx.y;
  const int tid = threadIdx.x;
  const int w = tid >> 6, l = tid & 63, g = l >> 4, c = l & 15;
  const int grp = w >> 2;             // kv half
  const int pw = w & 3;               // q-subtile / pair id
  const int kvbase = grp * 1024;

  // LDS: [Ka(4608) Va(4608) Kb(4608) Vb(4608) Ps(8x2304)] shorts = 73728 B
  __shared__ short smem[36864];
  short* Ks = smem + grp * 9216;          // this group's K chunk [64][72]
  short* Vs = smem + grp * 9216 + 4608;   // this group's V^T chunk [64][72]
  short* psw = smem + 18432 + w * 2304;   // per-wave P [32][72]

  const int qrow0 = qt * 128 + pw * 32;
  const short* Qbh = qhh + ((size_t)bh * SEQ + qrow0) * DK;
  const short* Qbl = qhl + ((size_t)bh * SEQ + qrow0) * DK;
  const short* Kbh = khh + (size_t)bh * SEQ * DK;
  const short* Vb  = vt  + (size_t)bh * DK * SEQ;           // [64][SEQ]
  const float* M0  = mask + (size_t)b * SEQ * SEQ + (size_t)(qrow0 + c) * SEQ;

  // staging: threads 0-255 stage group-A buffers, 256-511 group-B.
  // each thread: 16 contiguous shorts per buffer (K and V).
  const int sgrp = tid >> 8;
  const int tl = tid & 255;
  const int srow = tl >> 2, scol = (tl & 3) * 16;
  const int sofs = srow * 72 + scol;
  short* sK = smem + sgrp * 9216;
  short* sV = smem + sgrp * 9216 + 4608;
  const int skvb = sgrp * 1024;

  // Q frags (B-operand): lane c holds Q row q=mi*16+c, k = ks*32+g*8
  short8_t qfh[2][2], qfl[2][2];
#pragma unroll
  for (int mi = 0; mi < 2; ++mi)
#pragma unroll
    for (int ks = 0; ks < 2; ++ks) {
      qfh[mi][ks] = *(const short8_t*)(Qbh + (size_t)(mi * 16 + c) * DK + ks * 32 + g * 8);
      qfl[mi][ks] = *(const short8_t*)(Qbl + (size_t)(mi * 16 + c) * DK + ks * 32 + g * 8);
    }

  // prologue staging loads (this thread's group, chunk 0)
  short8_t rkh0 = *(const short8_t*)(Kbh + (size_t)(skvb + srow) * DK + scol);
  short8_t rkh1 = *(const short8_t*)(Kbh + (size_t)(skvb + srow) * DK + scol + 8);
  short8_t rv0  = *(const short8_t*)(Vb  + (size_t)srow * SEQ + skvb + scol);
  short8_t rv1  = *(const short8_t*)(Vb  + (size_t)srow * SEQ + skvb + scol + 8);

  f32x4_t o[4][2] = {};          // o[di][mi]: O^T rows d=di*16+g*4+j, col q
  float mrun[2] = {-1e30f, -1e30f};
  float lrun[2] = {0.f, 0.f};

  for (int t = 0; t < 16; ++t) {
    __syncthreads();             // prev iter's readers done
    *(short8_t*)(&sK[sofs]) = rkh0;
    *(short8_t*)(&sK[sofs + 8]) = rkh1;
    *(short8_t*)(&sV[sofs]) = rv0;
    *(short8_t*)(&sV[sofs + 8]) = rv1;
    __syncthreads();             // staged data visible

    // issue-early prefetch of this group's next chunk
    if (t + 1 < 16) {
      int kvn = skvb + (t + 1) * 64;
      rkh0 = *(const short8_t*)(Kbh + (size_t)(kvn + srow) * DK + scol);
      rkh1 = *(const short8_t*)(Kbh + (size_t)(kvn + srow) * DK + scol + 8);
      rv0  = *(const short8_t*)(Vb  + (size_t)srow * SEQ + kvn + scol);
      rv1  = *(const short8_t*)(Vb  + (size_t)srow * SEQ + kvn + scol + 8);
    }
    const int kvg = kvbase + t * 64;   // global kv offset for mask

    // ---- S^T = K_hi (Q_hi + Q_lo)^T : 2 chains, K frags from LDS ----
    f32x4_t sa[4][2] = {};       // sa[ni][mi]: rows kv=ni*16+g*4+j, col q
    __builtin_amdgcn_s_setprio(1);
#pragma unroll
    for (int ks = 0; ks < 2; ++ks) {
      short8_t ah[4];
#pragma unroll
      for (int ni = 0; ni < 4; ++ni)
        ah[ni] = *(const short8_t*)(&Ks[(ni * 16 + c) * 72 + ks * 32 + g * 8]);
#pragma unroll
      for (int ni = 0; ni < 4; ++ni)
#pragma unroll
        for (int mi = 0; mi < 2; ++mi) {
          sa[ni][mi] = __builtin_amdgcn_mfma_f32_16x16x32_bf16(
              ah[ni], qfh[mi][ks], sa[ni][mi], 0, 0, 0);
          sa[ni][mi] = __builtin_amdgcn_mfma_f32_16x16x32_bf16(
              ah[ni], qfl[mi][ks], sa[ni][mi], 0, 0, 0);
        }
    }
    __builtin_amdgcn_s_setprio(0);

    // ---- + mask * log2e (fma), direct loads ----
#pragma unroll
    for (int mi = 0; mi < 2; ++mi)
#pragma unroll
      for (int ni = 0; ni < 4; ++ni) {
        float4 mv = *(const float4*)(M0 + (size_t)(mi * 16) * SEQ + kvg + ni * 16 + g * 4);
        sa[ni][mi][0] = fmaf(mv.x, LOG2E, sa[ni][mi][0]);
        sa[ni][mi][1] = fmaf(mv.y, LOG2E, sa[ni][mi][1]);
        sa[ni][mi][2] = fmaf(mv.z, LOG2E, sa[ni][mi][2]);
        sa[ni][mi][3] = fmaf(mv.w, LOG2E, sa[ni][mi][3]);
      }

    // ---- online softmax in log2 space, defer-max (THR=8) ----
#pragma unroll
    for (int mi = 0; mi < 2; ++mi) {
      float tmx = sa[0][mi][0];
#pragma unroll
      for (int ni = 0; ni < 4; ++ni)
#pragma unroll
        for (int j = 0; j < 4; ++j) tmx = fmaxf(tmx, sa[ni][mi][j]);
      tmx = fmaxf(tmx, __shfl_xor(tmx, 16));
      tmx = fmaxf(tmx, __shfl_xor(tmx, 32));
      if (!__all(tmx - mrun[mi] <= 8.f)) {
        float mnew = fmaxf(mrun[mi], tmx);
        float sc = exp2f(mrun[mi] - mnew);
        mrun[mi] = mnew;
        lrun[mi] *= sc;
#pragma unroll
        for (int di = 0; di < 4; ++di)
#pragma unroll
          for (int j = 0; j < 4; ++j) o[di][mi][j] *= sc;
      }
      float psum = 0.f;
#pragma unroll
      for (int ni = 0; ni < 4; ++ni) {
        float p0 = exp2f(sa[ni][mi][0] - mrun[mi]);
        float p1 = exp2f(sa[ni][mi][1] - mrun[mi]);
        float p2 = exp2f(sa[ni][mi][2] - mrun[mi]);
        float p3 = exp2f(sa[ni][mi][3] - mrun[mi]);
        psum += (p0 + p1) + (p2 + p3);
        unsigned int u0 = cvt_pk_bf16(p0, p1);
        unsigned int u1 = cvt_pk_bf16(p2, p3);
        unsigned long long pu = ((unsigned long long)u1 << 32) | u0;
        *(unsigned long long*)(&psw[(mi * 16 + c) * 72 + ni * 16 + g * 4]) = pu;
      }
      lrun[mi] += psum;
    }

    // ---- O^T += V^T P^T : V frags from LDS ----
    __builtin_amdgcn_s_setprio(1);
#pragma unroll
    for (int ks = 0; ks < 2; ++ks) {
      short8_t pb[2];
#pragma unroll
      for (int mi = 0; mi < 2; ++mi)
        pb[mi] = *(const short8_t*)(&psw[(mi * 16 + c) * 72 + ks * 32 + g * 8]);
#pragma unroll
      for (int di = 0; di < 4; ++di) {
        short8_t av = *(const short8_t*)(&Vs[(di * 16 + c) * 72 + ks * 32 + g * 8]);
#pragma unroll
        for (int mi = 0; mi < 2; ++mi)
          o[di][mi] = __builtin_amdgcn_mfma_f32_16x16x32_bf16(
              av, pb[mi], o[di][mi], 0, 0, 0);
      }
    }
    __builtin_amdgcn_s_setprio(0);
  }

  // ---- in-block combine: group B dumps, group A merges + stores ----
  __syncthreads();               // all compute done; smem free for reuse
  // per-pair region: 32 q-rows x 72 floats: [0..63]=o, [64]=m, [65+g]=l(g)
  float* R = ((float*)smem) + pw * 2304;
  if (w >= 4) {
#pragma unroll
    for (int mi = 0; mi < 2; ++mi) {
      float* Rq = R + (mi * 16 + c) * 72;
#pragma unroll
      for (int di = 0; di < 4; ++di)
#pragma unroll
        for (int j = 0; j < 4; ++j)
          Rq[di * 16 + g * 4 + j] = o[di][mi][j];
      Rq[65 + g] = lrun[mi];
      if (g == 0) Rq[64] = mrun[mi];
    }
  }
  __syncthreads();
  if (w < 4) {
    short* Cb = ctx + ((size_t)b * SEQ + qrow0) * DFF + h * DK;
#pragma unroll
    for (int mi = 0; mi < 2; ++mi) {
      float* Rq = R + (mi * 16 + c) * 72;
      float mB = Rq[64], lB = Rq[65 + g];
      float M = fmaxf(mrun[mi], mB);
      float sA = exp2f(mrun[mi] - M);
      float sB = exp2f(mB - M);
      float lm = lrun[mi] * sA + lB * sB;   // per-g partial
      lm += __shfl_xor(lm, 16);
      lm += __shfl_xor(lm, 32);
      float inv = 1.f / lm;
#pragma unroll
      for (int di = 0; di < 4; ++di) {
        short4_t s4;
#pragma unroll
        for (int j = 0; j < 4; ++j) {
          float val = (o[di][mi][j] * sA + Rq[di * 16 + g * 4 + j] * sB) * inv;
          s4[j] = (short)f32_to_bf16(val);
        }
        *(short4_t*)(Cb + (size_t)(mi * 16 + c) * DFF + di * 16 + g * 4) = s4;
      }
    }
  }
}

// ---------------------------------------------------------------------------
extern "C" void kernel_launch(void* const* d_in, const int* in_sizes, int n_in,
                              void* d_out, int out_size, void* d_ws, size_t ws_size,
                              hipStream_t stream) {
  const float* q    = (const float*)d_in[0];
  const float* k    = (const float*)d_in[1];
  const float* v    = (const float*)d_in[2];
  const float* mask = (const float*)d_in[3];
  const float* Wq   = (const float*)d_in[4];
  const float* Wk   = (const float*)d_in[5];
  const float* Wv   = (const float*)d_in[6];
  const float* Wo   = (const float*)d_in[7];
  float* out = (float*)d_out;

  const size_t NQ = 4194304;   // 4096*1024
  const size_t NW = 1048576;   // 1024*1024
  short* ws   = (short*)d_ws;
  short* qbf  = ws;            // A0; reused as kh_h after Q-proj
  short* kbf  = ws + NQ;       // A1; reused as vtp after K-proj
  short* vbf  = ws + 2 * NQ;   // A2; reused as ctx after V-proj
  short* qh_h = ws + 3 * NQ;
  short* qh_l = ws + 4 * NQ;
  short* wbase = ws + 5 * NQ;  // [wq_h wq_l wk_h wk_l wv_h wv_l wob], NW each
  short* wq_h = wbase;
  short* wq_l = wbase + NW;
  short* wk_h = wbase + 2 * NW;
  short* wk_l = wbase + 3 * NW;
  short* wv_h = wbase + 4 * NW;
  short* wv_l = wbase + 5 * NW;
  short* wob  = wbase + 6 * NW;   // total 5*NQ + 7*NW = 56.6 MB

  short* kh_h = qbf;   // aliases (stream-ordered, safe)
  short* vtp  = kbf;   // V transposed [B,H,64,S]
  short* ctx  = vbf;

  cvt_x_kernel<<<dim3(4096, 3), 256, 0, stream>>>(q, k, v, ws, (int)NQ);
  cvt_w_kernel<<<dim3(1024, 4), 256, 0, stream>>>(Wq, Wk, Wv, Wo, wbase, (int)NW);

  dim3 gg(16, 32);   // N/64, M/128
  gemm_proj<0><<<gg, 256, 0, stream>>>(qbf, wq_h, wq_l, qh_h, qh_l, 4096, 1024);
  gemm_proj<1><<<gg, 256, 0, stream>>>(kbf, wk_h, wk_l, kh_h, nullptr, 4096, 1024);
  gemm_proj<2><<<gg, 256, 0, stream>>>(vbf, wv_h, wv_l, vtp, nullptr, 4096, 1024);

  attn_kernel<<<dim3(32, 16), 512, 0, stream>>>(qh_h, qh_l, kh_h, vtp, mask, ctx);

  gemm_out<<<gg, 256, 0, stream>>>(ctx, wob, out, 4096, 1024);
}

// Round 9
// 259.431 us; speedup vs baseline: 1.2591x; 1.2591x over previous
//
#include <hip/hip_runtime.h>
#include <hip/hip_bf16.h>

// ---------------------------------------------------------------------------
// T5 MHA: B=2, S=2048, D_FF=1024, H=16, DK=64, INNER=1024
// Precision: q carried hi+lo (2-chain QK vs k_hi); W's split for projections.
// Attn v7 (= v6 with register-fitted loops): 512 thr, 8 waves, in-block
// KV-SPLIT (waves 0-3 kv[0,1024), 4-7 kv[1024,2048)), q=32/wave.
// QK^T+softmax processed PER-MI (sa[4] not sa[4][2]) to stay under the
// 128-VGPR/4-wave cap that R8 blew (spill -> 293MB scratch writes).
// exp2 softmax (Q pre-scaled log2e), cvt_pk P-pack, defer-max, LDS combine.
// ---------------------------------------------------------------------------

typedef __attribute__((ext_vector_type(8))) short short8_t;   // 8 bf16 (4 VGPR)
typedef __attribute__((ext_vector_type(4))) short short4_t;
typedef __attribute__((ext_vector_type(4))) float f32x4_t;

#define SEQ 2048
#define HEADS 16
#define DK 64
#define DFF 1024
#define LOG2E 1.44269504088896340736f

__device__ __forceinline__ unsigned short f32_to_bf16(float f) {
  unsigned int u = __float_as_uint(f);
  u += 0x7FFFu + ((u >> 16) & 1u);   // round-to-nearest-even
  return (unsigned short)(u >> 16);
}
__device__ __forceinline__ float bf16_to_f32(unsigned short h) {
  return __uint_as_float(((unsigned int)h) << 16);
}
__device__ __forceinline__ unsigned int cvt_pk_bf16(float a, float b) {
  unsigned int r;
  asm("v_cvt_pk_bf16_f32 %0, %1, %2" : "=v"(r) : "v"(a), "v"(b));
  return r;
}

__device__ __forceinline__ void gload_lds16(const void* g, void* l) {
  __builtin_amdgcn_global_load_lds(
      (__attribute__((address_space(1))) void*)(g),
      (__attribute__((address_space(3))) void*)(l), 16, 0, 0);
}

// ---------------------------------------------------------------------------
// cvt_x: q/k/v fp32 -> bf16, one dispatch
// ---------------------------------------------------------------------------
__global__ void cvt_x_kernel(const float* __restrict__ q,
                             const float* __restrict__ k,
                             const float* __restrict__ v,
                             short* __restrict__ dst, int n) {
  const float* src = (blockIdx.y == 0) ? q : (blockIdx.y == 1) ? k : v;
  short* out = dst + (size_t)blockIdx.y * n;
  int i = (blockIdx.x * 256 + threadIdx.x) * 4;
  if (i >= n) return;
  float4 f = *(const float4*)(src + i);
  short4_t s;
  s[0] = (short)f32_to_bf16(f.x);
  s[1] = (short)f32_to_bf16(f.y);
  s[2] = (short)f32_to_bf16(f.z);
  s[3] = (short)f32_to_bf16(f.w);
  *(short4_t*)(out + i) = s;
}

// ---------------------------------------------------------------------------
// cvt_w: y<3 -> split W[y] into hi+lo pair; y==3 -> plain Wo
// ---------------------------------------------------------------------------
__global__ void cvt_w_kernel(const float* __restrict__ Wq,
                             const float* __restrict__ Wk,
                             const float* __restrict__ Wv,
                             const float* __restrict__ Wo,
                             short* __restrict__ wbase, int n) {
  int y = blockIdx.y;
  const float* src = (y == 0) ? Wq : (y == 1) ? Wk : (y == 2) ? Wv : Wo;
  int i = (blockIdx.x * 256 + threadIdx.x) * 4;
  if (i >= n) return;
  float4 f = *(const float4*)(src + i);
  float ff[4] = {f.x, f.y, f.z, f.w};
  if (y < 3) {
    short* hi = wbase + (size_t)(2 * y) * n;
    short* lo = wbase + (size_t)(2 * y + 1) * n;
    short4_t h, l;
#pragma unroll
    for (int j = 0; j < 4; ++j) {
      unsigned short hh = f32_to_bf16(ff[j]);
      h[j] = (short)hh;
      l[j] = (short)f32_to_bf16(ff[j] - bf16_to_f32(hh));
    }
    *(short4_t*)(hi + i) = h;
    *(short4_t*)(lo + i) = l;
  } else {
    short* out = wbase + (size_t)6 * n;
    short4_t s;
#pragma unroll
    for (int j = 0; j < 4; ++j) s[j] = (short)f32_to_bf16(ff[j]);
    *(short4_t*)(out + i) = s;
  }
}

// ---------------------------------------------------------------------------
// Projection GEMM: C[M,1024] = A[M,K] @ (Bh+Bl)[1024,K]^T, 2 MFMA chains.
// Tile 128M x 64N. EPI 0: Q hi+lo head-split, PRE-SCALED by log2e.
// EPI 1: K hi head-split. EPI 2: V hi TRANSPOSED [B,H,64,S].
// ---------------------------------------------------------------------------
template <int EPI>
__global__ __launch_bounds__(256, 2) void gemm_proj(
    const short* __restrict__ A, const short* __restrict__ Bh,
    const short* __restrict__ Bl, short* __restrict__ Ohi,
    short* __restrict__ Olo, int M, int K) {
  __shared__ short As[128 * 32];
  __shared__ short Bsh[64 * 32];
  __shared__ short Bsl[64 * 32];

  const int tid = threadIdx.x;
  const int w = tid >> 6, l = tid & 63, g = l >> 4, c = l & 15;
  const int wr = w >> 1, wc = w & 1;
  const int m0 = blockIdx.y * 128, n0 = blockIdx.x * 64;

  f32x4_t acc[4][2] = {};

  for (int k0 = 0; k0 < K; k0 += 32) {
#pragma unroll
    for (int j = 0; j < 2; ++j) {
      int e = (w * 2 + j) * 512 + l * 8;
      int r = e >> 5, cc = e & 31;
      gload_lds16(A + (size_t)(m0 + r) * K + k0 + cc, &As[(w * 2 + j) * 512]);
    }
    {
      int e = w * 512 + l * 8;
      int r = e >> 5, cc = e & 31;
      gload_lds16(Bh + (size_t)(n0 + r) * K + k0 + cc, &Bsh[w * 512]);
      gload_lds16(Bl + (size_t)(n0 + r) * K + k0 + cc, &Bsl[w * 512]);
    }
    __syncthreads();

    short8_t a[4], bh[2], bl[2];
#pragma unroll
    for (int mi = 0; mi < 4; ++mi)
      a[mi] = *(const short8_t*)(&As[(wr * 64 + mi * 16 + c) * 32 + g * 8]);
#pragma unroll
    for (int ni = 0; ni < 2; ++ni) {
      bh[ni] = *(const short8_t*)(&Bsh[(wc * 32 + ni * 16 + c) * 32 + g * 8]);
      bl[ni] = *(const short8_t*)(&Bsl[(wc * 32 + ni * 16 + c) * 32 + g * 8]);
    }
#pragma unroll
    for (int mi = 0; mi < 4; ++mi)
#pragma unroll
      for (int ni = 0; ni < 2; ++ni) {
        acc[mi][ni] = __builtin_amdgcn_mfma_f32_16x16x32_bf16(
            a[mi], bh[ni], acc[mi][ni], 0, 0, 0);
        acc[mi][ni] = __builtin_amdgcn_mfma_f32_16x16x32_bf16(
            a[mi], bl[ni], acc[mi][ni], 0, 0, 0);
      }
    __syncthreads();
  }

#pragma unroll
  for (int mi = 0; mi < 4; ++mi) {
#pragma unroll
    for (int ni = 0; ni < 2; ++ni) {
      int col = n0 + wc * 32 + ni * 16 + c;
      int hh = col >> 6, dd = col & 63;
      if (EPI == 2) {
        int row0 = m0 + wr * 64 + mi * 16 + g * 4;
        int bb = row0 >> 11, ss0 = row0 & 2047;
        short4_t s4;
#pragma unroll
        for (int j = 0; j < 4; ++j) s4[j] = (short)f32_to_bf16(acc[mi][ni][j]);
        *(short4_t*)(&Ohi[(((size_t)bb * HEADS + hh) * DK + dd) * SEQ + ss0]) = s4;
      } else {
#pragma unroll
        for (int j = 0; j < 4; ++j) {
          int row = m0 + wr * 64 + mi * 16 + g * 4 + j;
          int bb = row >> 11, ss = row & 2047;
          size_t idx = (((size_t)bb * HEADS + hh) * SEQ + ss) * DK + dd;
          float x = acc[mi][ni][j];
          if (EPI == 0) x *= LOG2E;   // fold log2e into Q for exp2 softmax
          unsigned short xh = f32_to_bf16(x);
          Ohi[idx] = (short)xh;
          if (EPI == 0)
            Olo[idx] = (short)f32_to_bf16(x - bf16_to_f32(xh));
        }
      }
    }
  }
}

// ---------------------------------------------------------------------------
// Output GEMM: O[M,1024] fp32 = A[M,K] @ Bw[1024,K]^T, plain bf16, 1 chain.
// ---------------------------------------------------------------------------
__global__ __launch_bounds__(256, 2) void gemm_out(
    const short* __restrict__ A, const short* __restrict__ Bw,
    float* __restrict__ O, int M, int K) {
  __shared__ short As[128 * 32];
  __shared__ short Bs[64 * 32];

  const int tid = threadIdx.x;
  const int w = tid >> 6, l = tid & 63, g = l >> 4, c = l & 15;
  const int wr = w >> 1, wc = w & 1;
  const int m0 = blockIdx.y * 128, n0 = blockIdx.x * 64;

  f32x4_t acc[4][2] = {};

  for (int k0 = 0; k0 < K; k0 += 32) {
#pragma unroll
    for (int j = 0; j < 2; ++j) {
      int e = (w * 2 + j) * 512 + l * 8;
      int r = e >> 5, cc = e & 31;
      gload_lds16(A + (size_t)(m0 + r) * K + k0 + cc, &As[(w * 2 + j) * 512]);
    }
    {
      int e = w * 512 + l * 8;
      int r = e >> 5, cc = e & 31;
      gload_lds16(Bw + (size_t)(n0 + r) * K + k0 + cc, &Bs[w * 512]);
    }
    __syncthreads();

    short8_t a[4], b[2];
#pragma unroll
    for (int mi = 0; mi < 4; ++mi)
      a[mi] = *(const short8_t*)(&As[(wr * 64 + mi * 16 + c) * 32 + g * 8]);
#pragma unroll
    for (int ni = 0; ni < 2; ++ni)
      b[ni] = *(const short8_t*)(&Bs[(wc * 32 + ni * 16 + c) * 32 + g * 8]);
#pragma unroll
    for (int mi = 0; mi < 4; ++mi)
#pragma unroll
      for (int ni = 0; ni < 2; ++ni)
        acc[mi][ni] = __builtin_amdgcn_mfma_f32_16x16x32_bf16(
            a[mi], b[ni], acc[mi][ni], 0, 0, 0);
    __syncthreads();
  }

#pragma unroll
  for (int mi = 0; mi < 4; ++mi)
#pragma unroll
    for (int ni = 0; ni < 2; ++ni) {
      int col = n0 + wc * 32 + ni * 16 + c;
#pragma unroll
      for (int j = 0; j < 4; ++j) {
        int row = m0 + wr * 64 + mi * 16 + g * 4 + j;
        O[(size_t)row * DFF + col] = acc[mi][ni][j];
      }
    }
}

// ---------------------------------------------------------------------------
// Flash attention v7. Grid (B*H, S/128), 512 thr = 8 waves.
// Wave w: kv-group grp=w>>2, q-subtile pw=w&3 (32 q-rows). 16 chunks/group.
// QK^T + softmax PER-MI (register fit). PV both mi. LDS end-combine.
// ---------------------------------------------------------------------------
__global__ __launch_bounds__(512, 4) void attn_kernel(
    const short* __restrict__ qhh, const short* __restrict__ qhl,
    const short* __restrict__ khh, const short* __restrict__ vt,
    const float* __restrict__ mask, short* __restrict__ ctx) {
  const int bh = blockIdx.x;
  const int b = bh >> 4;
  const int h = bh & 15;
  const int qt = blockIdx.y;
  const int tid = threadIdx.x;
  const int w = tid >> 6, l = tid & 63, g = l >> 4, c = l & 15;
  const int grp = w >> 2;             // kv half
  const int pw = w & 3;               // q-subtile / pair id
  const int kvbase = grp * 1024;

  // LDS: [Ka(4608) Va(4608) Kb(4608) Vb(4608) Ps(8x2304)] shorts = 73728 B
  __shared__ short smem[36864];
  short* Ks = smem + grp * 9216;          // this group's K chunk [64][72]
  short* Vs = smem + grp * 9216 + 4608;   // this group's V^T chunk [64][72]
  short* psw = smem + 18432 + w * 2304;   // per-wave P [32][72]

  const int qrow0 = qt * 128 + pw * 32;
  const short* Qbh = qhh + ((size_t)bh * SEQ + qrow0) * DK;
  const short* Qbl = qhl + ((size_t)bh * SEQ + qrow0) * DK;
  const short* Kbh = khh + (size_t)bh * SEQ * DK;
  const short* Vb  = vt  + (size_t)bh * DK * SEQ;           // [64][SEQ]
  const float* M0  = mask + (size_t)b * SEQ * SEQ + (size_t)(qrow0 + c) * SEQ;

  // staging: threads 0-255 stage group-A buffers, 256-511 group-B.
  const int sgrp = tid >> 8;
  const int tl = tid & 255;
  const int srow = tl >> 2, scol = (tl & 3) * 16;
  const int sofs = srow * 72 + scol;
  short* sK = smem + sgrp * 9216;
  short* sV = smem + sgrp * 9216 + 4608;
  const int skvb = sgrp * 1024;

  // Q frags (B-operand): lane c holds Q row q=mi*16+c, k = ks*32+g*8
  short8_t qfh[2][2], qfl[2][2];
#pragma unroll
  for (int mi = 0; mi < 2; ++mi)
#pragma unroll
    for (int ks = 0; ks < 2; ++ks) {
      qfh[mi][ks] = *(const short8_t*)(Qbh + (size_t)(mi * 16 + c) * DK + ks * 32 + g * 8);
      qfl[mi][ks] = *(const short8_t*)(Qbl + (size_t)(mi * 16 + c) * DK + ks * 32 + g * 8);
    }

  // prologue staging loads (this thread's group, chunk 0)
  short8_t rkh0 = *(const short8_t*)(Kbh + (size_t)(skvb + srow) * DK + scol);
  short8_t rkh1 = *(const short8_t*)(Kbh + (size_t)(skvb + srow) * DK + scol + 8);
  short8_t rv0  = *(const short8_t*)(Vb  + (size_t)srow * SEQ + skvb + scol);
  short8_t rv1  = *(const short8_t*)(Vb  + (size_t)srow * SEQ + skvb + scol + 8);

  f32x4_t o[4][2] = {};          // o[di][mi]: O^T rows d=di*16+g*4+j, col q
  float mrun[2] = {-1e30f, -1e30f};
  float lrun[2] = {0.f, 0.f};

  for (int t = 0; t < 16; ++t) {
    __syncthreads();             // prev iter's readers done
    *(short8_t*)(&sK[sofs]) = rkh0;
    *(short8_t*)(&sK[sofs + 8]) = rkh1;
    *(short8_t*)(&sV[sofs]) = rv0;
    *(short8_t*)(&sV[sofs + 8]) = rv1;
    __syncthreads();             // staged data visible

    // issue-early prefetch of this group's next chunk
    if (t + 1 < 16) {
      int kvn = skvb + (t + 1) * 64;
      rkh0 = *(const short8_t*)(Kbh + (size_t)(kvn + srow) * DK + scol);
      rkh1 = *(const short8_t*)(Kbh + (size_t)(kvn + srow) * DK + scol + 8);
      rv0  = *(const short8_t*)(Vb  + (size_t)srow * SEQ + kvn + scol);
      rv1  = *(const short8_t*)(Vb  + (size_t)srow * SEQ + kvn + scol + 8);
    }
    const int kvg = kvbase + t * 64;   // global kv offset for mask

    // ---- per-mi: S^T = K_hi (Q_hi + Q_lo)^T, mask, softmax, P-store ----
#pragma unroll
    for (int mi = 0; mi < 2; ++mi) {
      f32x4_t sa[4] = {};        // sa[ni]: rows kv=ni*16+g*4+j, col q
      __builtin_amdgcn_s_setprio(1);
#pragma unroll
      for (int ks = 0; ks < 2; ++ks) {
#pragma unroll
        for (int ni = 0; ni < 4; ++ni) {
          short8_t ah = *(const short8_t*)(&Ks[(ni * 16 + c) * 72 + ks * 32 + g * 8]);
          sa[ni] = __builtin_amdgcn_mfma_f32_16x16x32_bf16(
              ah, qfh[mi][ks], sa[ni], 0, 0, 0);
          sa[ni] = __builtin_amdgcn_mfma_f32_16x16x32_bf16(
              ah, qfl[mi][ks], sa[ni], 0, 0, 0);
        }
      }
      __builtin_amdgcn_s_setprio(0);

      // + mask * log2e (fma), direct loads
#pragma unroll
      for (int ni = 0; ni < 4; ++ni) {
        float4 mv = *(const float4*)(M0 + (size_t)(mi * 16) * SEQ + kvg + ni * 16 + g * 4);
        sa[ni][0] = fmaf(mv.x, LOG2E, sa[ni][0]);
        sa[ni][1] = fmaf(mv.y, LOG2E, sa[ni][1]);
        sa[ni][2] = fmaf(mv.z, LOG2E, sa[ni][2]);
        sa[ni][3] = fmaf(mv.w, LOG2E, sa[ni][3]);
      }

      // online softmax in log2 space, defer-max (THR=8)
      float tmx = sa[0][0];
#pragma unroll
      for (int ni = 0; ni < 4; ++ni)
#pragma unroll
        for (int j = 0; j < 4; ++j) tmx = fmaxf(tmx, sa[ni][j]);
      tmx = fmaxf(tmx, __shfl_xor(tmx, 16));
      tmx = fmaxf(tmx, __shfl_xor(tmx, 32));
      if (!__all(tmx - mrun[mi] <= 8.f)) {
        float mnew = fmaxf(mrun[mi], tmx);
        float sc = exp2f(mrun[mi] - mnew);
        mrun[mi] = mnew;
        lrun[mi] *= sc;
#pragma unroll
        for (int di = 0; di < 4; ++di)
#pragma unroll
          for (int j = 0; j < 4; ++j) o[di][mi][j] *= sc;
      }
      float psum = 0.f;
#pragma unroll
      for (int ni = 0; ni < 4; ++ni) {
        float p0 = exp2f(sa[ni][0] - mrun[mi]);
        float p1 = exp2f(sa[ni][1] - mrun[mi]);
        float p2 = exp2f(sa[ni][2] - mrun[mi]);
        float p3 = exp2f(sa[ni][3] - mrun[mi]);
        psum += (p0 + p1) + (p2 + p3);
        unsigned int u0 = cvt_pk_bf16(p0, p1);
        unsigned int u1 = cvt_pk_bf16(p2, p3);
        unsigned long long pu = ((unsigned long long)u1 << 32) | u0;
        *(unsigned long long*)(&psw[(mi * 16 + c) * 72 + ni * 16 + g * 4]) = pu;
      }
      lrun[mi] += psum;
    }

    // ---- O^T += V^T P^T : V frags from LDS ----
    __builtin_amdgcn_s_setprio(1);
#pragma unroll
    for (int ks = 0; ks < 2; ++ks) {
      short8_t pb[2];
#pragma unroll
      for (int mi = 0; mi < 2; ++mi)
        pb[mi] = *(const short8_t*)(&psw[(mi * 16 + c) * 72 + ks * 32 + g * 8]);
#pragma unroll
      for (int di = 0; di < 4; ++di) {
        short8_t av = *(const short8_t*)(&Vs[(di * 16 + c) * 72 + ks * 32 + g * 8]);
#pragma unroll
        for (int mi = 0; mi < 2; ++mi)
          o[di][mi] = __builtin_amdgcn_mfma_f32_16x16x32_bf16(
              av, pb[mi], o[di][mi], 0, 0, 0);
      }
    }
    __builtin_amdgcn_s_setprio(0);
  }

  // ---- in-block combine: group B dumps, group A merges + stores ----
  __syncthreads();               // all compute done; smem free for reuse
  // per-pair region: 32 q-rows x 72 floats: [0..63]=o, [64]=m, [65+g]=l(g)
  float* R = ((float*)smem) + pw * 2304;
  if (w >= 4) {
#pragma unroll
    for (int mi = 0; mi < 2; ++mi) {
      float* Rq = R + (mi * 16 + c) * 72;
#pragma unroll
      for (int di = 0; di < 4; ++di)
#pragma unroll
        for (int j = 0; j < 4; ++j)
          Rq[di * 16 + g * 4 + j] = o[di][mi][j];
      Rq[65 + g] = lrun[mi];
      if (g == 0) Rq[64] = mrun[mi];
    }
  }
  __syncthreads();
  if (w < 4) {
    short* Cb = ctx + ((size_t)b * SEQ + qrow0) * DFF + h * DK;
#pragma unroll
    for (int mi = 0; mi < 2; ++mi) {
      float* Rq = R + (mi * 16 + c) * 72;
      float mB = Rq[64], lB = Rq[65 + g];
      float M = fmaxf(mrun[mi], mB);
      float sA = exp2f(mrun[mi] - M);
      float sB = exp2f(mB - M);
      float lm = lrun[mi] * sA + lB * sB;   // per-g partial
      lm += __shfl_xor(lm, 16);
      lm += __shfl_xor(lm, 32);
      float inv = 1.f / lm;
#pragma unroll
      for (int di = 0; di < 4; ++di) {
        short4_t s4;
#pragma unroll
        for (int j = 0; j < 4; ++j) {
          float val = (o[di][mi][j] * sA + Rq[di * 16 + g * 4 + j] * sB) * inv;
          s4[j] = (short)f32_to_bf16(val);
        }
        *(short4_t*)(Cb + (size_t)(mi * 16 + c) * DFF + di * 16 + g * 4) = s4;
      }
    }
  }
}

// ---------------------------------------------------------------------------
extern "C" void kernel_launch(void* const* d_in, const int* in_sizes, int n_in,
                              void* d_out, int out_size, void* d_ws, size_t ws_size,
                              hipStream_t stream) {
  const float* q    = (const float*)d_in[0];
  const float* k    = (const float*)d_in[1];
  const float* v    = (const float*)d_in[2];
  const float* mask = (const float*)d_in[3];
  const float* Wq   = (const float*)d_in[4];
  const float* Wk   = (const float*)d_in[5];
  const float* Wv   = (const float*)d_in[6];
  const float* Wo   = (const float*)d_in[7];
  float* out = (float*)d_out;

  const size_t NQ = 4194304;   // 4096*1024
  const size_t NW = 1048576;   // 1024*1024
  short* ws   = (short*)d_ws;
  short* qbf  = ws;            // A0; reused as kh_h after Q-proj
  short* kbf  = ws + NQ;       // A1; reused as vtp after K-proj
  short* vbf  = ws + 2 * NQ;   // A2; reused as ctx after V-proj
  short* qh_h = ws + 3 * NQ;
  short* qh_l = ws + 4 * NQ;
  short* wbase = ws + 5 * NQ;  // [wq_h wq_l wk_h wk_l wv_h wv_l wob], NW each
  short* wq_h = wbase;
  short* wq_l = wbase + NW;
  short* wk_h = wbase + 2 * NW;
  short* wk_l = wbase + 3 * NW;
  short* wv_h = wbase + 4 * NW;
  short* wv_l = wbase + 5 * NW;
  short* wob  = wbase + 6 * NW;   // total 5*NQ + 7*NW = 56.6 MB

  short* kh_h = qbf;   // aliases (stream-ordered, safe)
  short* vtp  = kbf;   // V transposed [B,H,64,S]
  short* ctx  = vbf;

  cvt_x_kernel<<<dim3(4096, 3), 256, 0, stream>>>(q, k, v, ws, (int)NQ);
  cvt_w_kernel<<<dim3(1024, 4), 256, 0, stream>>>(Wq, Wk, Wv, Wo, wbase, (int)NW);

  dim3 gg(16, 32);   // N/64, M/128
  gemm_proj<0><<<gg, 256, 0, stream>>>(qbf, wq_h, wq_l, qh_h, qh_l, 4096, 1024);
  gemm_proj<1><<<gg, 256, 0, stream>>>(kbf, wk_h, wk_l, kh_h, nullptr, 4096, 1024);
  gemm_proj<2><<<gg, 256, 0, stream>>>(vbf, wv_h, wv_l, vtp, nullptr, 4096, 1024);

  attn_kernel<<<dim3(32, 16), 512, 0, stream>>>(qh_h, qh_l, kh_h, vtp, mask, ctx);

  gemm_out<<<gg, 256, 0, stream>>>(ctx, wob, out, 4096, 1024);
}

// Round 10
// 215.033 us; speedup vs baseline: 1.5191x; 1.2065x over previous
//
#include <hip/hip_runtime.h>
#include <hip/hip_bf16.h>

// ---------------------------------------------------------------------------
// T5 MHA: B=2, S=2048, D_FF=1024, H=16, DK=64, INNER=1024
// Precision: q carried hi+lo (2-chain QK vs k_hi); W's split for projections.
// Attn v8 = R7's proven 8-wave/q=16 structure (VGPR 56, no spill) +
//   (a) LDS stride 72->76: kills the 8-way bank conflict on ds_read_b128
//   (b) exp2 softmax (Q pre-scaled log2e), fmaf mask, cvt_pk P-pack, defer-max
// NO register-state growth vs R7 (R8/R9 lesson: launch_bounds(512,4)
// effectively caps at 64 VGPR -> anything bigger spills to scratch).
// ---------------------------------------------------------------------------

typedef __attribute__((ext_vector_type(8))) short short8_t;   // 8 bf16 (4 VGPR)
typedef __attribute__((ext_vector_type(4))) short short4_t;
typedef __attribute__((ext_vector_type(4))) float f32x4_t;

#define SEQ 2048
#define HEADS 16
#define DK 64
#define DFF 1024
#define LOG2E 1.44269504088896340736f
#define LSTR 76   // LDS row stride (bf16 elems): 38 dwords == 6 mod 32 banks

__device__ __forceinline__ unsigned short f32_to_bf16(float f) {
  unsigned int u = __float_as_uint(f);
  u += 0x7FFFu + ((u >> 16) & 1u);   // round-to-nearest-even
  return (unsigned short)(u >> 16);
}
__device__ __forceinline__ float bf16_to_f32(unsigned short h) {
  return __uint_as_float(((unsigned int)h) << 16);
}
__device__ __forceinline__ unsigned int cvt_pk_bf16(float a, float b) {
  unsigned int r;
  asm("v_cvt_pk_bf16_f32 %0, %1, %2" : "=v"(r) : "v"(a), "v"(b));
  return r;
}

__device__ __forceinline__ void gload_lds16(const void* g, void* l) {
  __builtin_amdgcn_global_load_lds(
      (__attribute__((address_space(1))) void*)(g),
      (__attribute__((address_space(3))) void*)(l), 16, 0, 0);
}

// ---------------------------------------------------------------------------
// cvt_x: q/k/v fp32 -> bf16, one dispatch
// ---------------------------------------------------------------------------
__global__ void cvt_x_kernel(const float* __restrict__ q,
                             const float* __restrict__ k,
                             const float* __restrict__ v,
                             short* __restrict__ dst, int n) {
  const float* src = (blockIdx.y == 0) ? q : (blockIdx.y == 1) ? k : v;
  short* out = dst + (size_t)blockIdx.y * n;
  int i = (blockIdx.x * 256 + threadIdx.x) * 4;
  if (i >= n) return;
  float4 f = *(const float4*)(src + i);
  short4_t s;
  s[0] = (short)f32_to_bf16(f.x);
  s[1] = (short)f32_to_bf16(f.y);
  s[2] = (short)f32_to_bf16(f.z);
  s[3] = (short)f32_to_bf16(f.w);
  *(short4_t*)(out + i) = s;
}

// ---------------------------------------------------------------------------
// cvt_w: y<3 -> split W[y] into hi+lo pair; y==3 -> plain Wo
// ---------------------------------------------------------------------------
__global__ void cvt_w_kernel(const float* __restrict__ Wq,
                             const float* __restrict__ Wk,
                             const float* __restrict__ Wv,
                             const float* __restrict__ Wo,
                             short* __restrict__ wbase, int n) {
  int y = blockIdx.y;
  const float* src = (y == 0) ? Wq : (y == 1) ? Wk : (y == 2) ? Wv : Wo;
  int i = (blockIdx.x * 256 + threadIdx.x) * 4;
  if (i >= n) return;
  float4 f = *(const float4*)(src + i);
  float ff[4] = {f.x, f.y, f.z, f.w};
  if (y < 3) {
    short* hi = wbase + (size_t)(2 * y) * n;
    short* lo = wbase + (size_t)(2 * y + 1) * n;
    short4_t h, l;
#pragma unroll
    for (int j = 0; j < 4; ++j) {
      unsigned short hh = f32_to_bf16(ff[j]);
      h[j] = (short)hh;
      l[j] = (short)f32_to_bf16(ff[j] - bf16_to_f32(hh));
    }
    *(short4_t*)(hi + i) = h;
    *(short4_t*)(lo + i) = l;
  } else {
    short* out = wbase + (size_t)6 * n;
    short4_t s;
#pragma unroll
    for (int j = 0; j < 4; ++j) s[j] = (short)f32_to_bf16(ff[j]);
    *(short4_t*)(out + i) = s;
  }
}

// ---------------------------------------------------------------------------
// Projection GEMM: C[M,1024] = A[M,K] @ (Bh+Bl)[1024,K]^T, 2 MFMA chains.
// Tile 128M x 64N. EPI 0: Q hi+lo head-split, PRE-SCALED by log2e.
// EPI 1: K hi head-split. EPI 2: V hi TRANSPOSED [B,H,64,S].
// ---------------------------------------------------------------------------
template <int EPI>
__global__ __launch_bounds__(256, 2) void gemm_proj(
    const short* __restrict__ A, const short* __restrict__ Bh,
    const short* __restrict__ Bl, short* __restrict__ Ohi,
    short* __restrict__ Olo, int M, int K) {
  __shared__ short As[128 * 32];
  __shared__ short Bsh[64 * 32];
  __shared__ short Bsl[64 * 32];

  const int tid = threadIdx.x;
  const int w = tid >> 6, l = tid & 63, g = l >> 4, c = l & 15;
  const int wr = w >> 1, wc = w & 1;
  const int m0 = blockIdx.y * 128, n0 = blockIdx.x * 64;

  f32x4_t acc[4][2] = {};

  for (int k0 = 0; k0 < K; k0 += 32) {
#pragma unroll
    for (int j = 0; j < 2; ++j) {
      int e = (w * 2 + j) * 512 + l * 8;
      int r = e >> 5, cc = e & 31;
      gload_lds16(A + (size_t)(m0 + r) * K + k0 + cc, &As[(w * 2 + j) * 512]);
    }
    {
      int e = w * 512 + l * 8;
      int r = e >> 5, cc = e & 31;
      gload_lds16(Bh + (size_t)(n0 + r) * K + k0 + cc, &Bsh[w * 512]);
      gload_lds16(Bl + (size_t)(n0 + r) * K + k0 + cc, &Bsl[w * 512]);
    }
    __syncthreads();

    short8_t a[4], bh[2], bl[2];
#pragma unroll
    for (int mi = 0; mi < 4; ++mi)
      a[mi] = *(const short8_t*)(&As[(wr * 64 + mi * 16 + c) * 32 + g * 8]);
#pragma unroll
    for (int ni = 0; ni < 2; ++ni) {
      bh[ni] = *(const short8_t*)(&Bsh[(wc * 32 + ni * 16 + c) * 32 + g * 8]);
      bl[ni] = *(const short8_t*)(&Bsl[(wc * 32 + ni * 16 + c) * 32 + g * 8]);
    }
#pragma unroll
    for (int mi = 0; mi < 4; ++mi)
#pragma unroll
      for (int ni = 0; ni < 2; ++ni) {
        acc[mi][ni] = __builtin_amdgcn_mfma_f32_16x16x32_bf16(
            a[mi], bh[ni], acc[mi][ni], 0, 0, 0);
        acc[mi][ni] = __builtin_amdgcn_mfma_f32_16x16x32_bf16(
            a[mi], bl[ni], acc[mi][ni], 0, 0, 0);
      }
    __syncthreads();
  }

#pragma unroll
  for (int mi = 0; mi < 4; ++mi) {
#pragma unroll
    for (int ni = 0; ni < 2; ++ni) {
      int col = n0 + wc * 32 + ni * 16 + c;
      int hh = col >> 6, dd = col & 63;
      if (EPI == 2) {
        int row0 = m0 + wr * 64 + mi * 16 + g * 4;
        int bb = row0 >> 11, ss0 = row0 & 2047;
        short4_t s4;
#pragma unroll
        for (int j = 0; j < 4; ++j) s4[j] = (short)f32_to_bf16(acc[mi][ni][j]);
        *(short4_t*)(&Ohi[(((size_t)bb * HEADS + hh) * DK + dd) * SEQ + ss0]) = s4;
      } else {
#pragma unroll
        for (int j = 0; j < 4; ++j) {
          int row = m0 + wr * 64 + mi * 16 + g * 4 + j;
          int bb = row >> 11, ss = row & 2047;
          size_t idx = (((size_t)bb * HEADS + hh) * SEQ + ss) * DK + dd;
          float x = acc[mi][ni][j];
          if (EPI == 0) x *= LOG2E;   // fold log2e into Q for exp2 softmax
          unsigned short xh = f32_to_bf16(x);
          Ohi[idx] = (short)xh;
          if (EPI == 0)
            Olo[idx] = (short)f32_to_bf16(x - bf16_to_f32(xh));
        }
      }
    }
  }
}

// ---------------------------------------------------------------------------
// Output GEMM: O[M,1024] fp32 = A[M,K] @ Bw[1024,K]^T, plain bf16, 1 chain.
// ---------------------------------------------------------------------------
__global__ __launch_bounds__(256, 2) void gemm_out(
    const short* __restrict__ A, const short* __restrict__ Bw,
    float* __restrict__ O, int M, int K) {
  __shared__ short As[128 * 32];
  __shared__ short Bs[64 * 32];

  const int tid = threadIdx.x;
  const int w = tid >> 6, l = tid & 63, g = l >> 4, c = l & 15;
  const int wr = w >> 1, wc = w & 1;
  const int m0 = blockIdx.y * 128, n0 = blockIdx.x * 64;

  f32x4_t acc[4][2] = {};

  for (int k0 = 0; k0 < K; k0 += 32) {
#pragma unroll
    for (int j = 0; j < 2; ++j) {
      int e = (w * 2 + j) * 512 + l * 8;
      int r = e >> 5, cc = e & 31;
      gload_lds16(A + (size_t)(m0 + r) * K + k0 + cc, &As[(w * 2 + j) * 512]);
    }
    {
      int e = w * 512 + l * 8;
      int r = e >> 5, cc = e & 31;
      gload_lds16(Bw + (size_t)(n0 + r) * K + k0 + cc, &Bs[w * 512]);
    }
    __syncthreads();

    short8_t a[4], b[2];
#pragma unroll
    for (int mi = 0; mi < 4; ++mi)
      a[mi] = *(const short8_t*)(&As[(wr * 64 + mi * 16 + c) * 32 + g * 8]);
#pragma unroll
    for (int ni = 0; ni < 2; ++ni)
      b[ni] = *(const short8_t*)(&Bs[(wc * 32 + ni * 16 + c) * 32 + g * 8]);
#pragma unroll
    for (int mi = 0; mi < 4; ++mi)
#pragma unroll
      for (int ni = 0; ni < 2; ++ni)
        acc[mi][ni] = __builtin_amdgcn_mfma_f32_16x16x32_bf16(
            a[mi], b[ni], acc[mi][ni], 0, 0, 0);
    __syncthreads();
  }

#pragma unroll
  for (int mi = 0; mi < 4; ++mi)
#pragma unroll
    for (int ni = 0; ni < 2; ++ni) {
      int col = n0 + wc * 32 + ni * 16 + c;
#pragma unroll
      for (int j = 0; j < 4; ++j) {
        int row = m0 + wr * 64 + mi * 16 + g * 4 + j;
        O[(size_t)row * DFF + col] = acc[mi][ni][j];
      }
    }
}

// ---------------------------------------------------------------------------
// Flash attention v8. Grid (B*H, S/128), 512 thr = 8 waves x 16 q-rows.
// 2 blocks/CU -> 4 waves/SIMD. S^T: mfma(A=K_hi rows kv, B=Q rows q).
// PV: O^T = mfma(A=V^T rows d, B=P rows q). K_hi + V^T staged in LDS
// (stride 76 = conflict-fixed); issue-early K/V prefetch; mask reg prefetch;
// exp2 softmax with defer-max; cvt_pk P-pack.
// ---------------------------------------------------------------------------
__global__ __launch_bounds__(512, 4) void attn_kernel(
    const short* __restrict__ qhh, const short* __restrict__ qhl,
    const short* __restrict__ khh, const short* __restrict__ vt,
    const float* __restrict__ mask, short* __restrict__ ctx) {
  const int bh = blockIdx.x;
  const int b = bh >> 4;
  const int h = bh & 15;
  const int qt = blockIdx.y;
  const int tid = threadIdx.x;
  const int w = tid >> 6, l = tid & 63, g = l >> 4, c = l & 15;

  __shared__ short Khs[64 * LSTR];      // K chunk hi [kv][k]
  __shared__ short Vts[64 * LSTR];      // V^T chunk [d][kv]
  __shared__ short Ps[8][16 * LSTR];    // per-wave P tile [q=16][kv]
  short* psw = &Ps[w][0];

  const int qrow0 = qt * 128 + w * 16;
  const short* Qbh = qhh + ((size_t)bh * SEQ + qrow0) * DK;
  const short* Qbl = qhl + ((size_t)bh * SEQ + qrow0) * DK;
  const short* Kbh = khh + (size_t)bh * SEQ * DK;
  const short* Vb  = vt  + (size_t)bh * DK * SEQ;           // [64][SEQ]
  const float* M0  = mask + (size_t)b * SEQ * SEQ + (size_t)(qrow0 + c) * SEQ;

  // staging: 512 threads x 1 short8 per buffer = full 64x64 coverage
  const int srow = tid >> 3;            // 0..63
  const int scol = (tid & 7) * 8;       // 0..56
  const int sofs = srow * LSTR + scol;

  // Q frags (B-operand): lane c holds Q row q=c, k = ks*32+g*8
  short8_t qfh[2], qfl[2];
#pragma unroll
  for (int ks = 0; ks < 2; ++ks) {
    qfh[ks] = *(const short8_t*)(Qbh + (size_t)c * DK + ks * 32 + g * 8);
    qfl[ks] = *(const short8_t*)(Qbl + (size_t)c * DK + ks * 32 + g * 8);
  }

  // prologue: chunk-0 staging regs + chunk-0 mask regs
  short8_t rkh = *(const short8_t*)(Kbh + (size_t)srow * DK + scol);
  short8_t rv  = *(const short8_t*)(Vb  + (size_t)srow * SEQ + scol);
  float4 mpre[4];
#pragma unroll
  for (int ni = 0; ni < 4; ++ni)
    mpre[ni] = *(const float4*)(M0 + ni * 16 + g * 4);

  f32x4_t o[4] = {};             // o[di]: O^T rows d=di*16+g*4+j, col q=c
  float mrun = -1e30f;
  float lrun = 0.f;

  for (int kv0 = 0; kv0 < SEQ; kv0 += 64) {
    __syncthreads();             // prev iter's readers done
    *(short8_t*)(&Khs[sofs]) = rkh;
    *(short8_t*)(&Vts[sofs]) = rv;
    __syncthreads();             // staged data visible to all waves

    const int kv1 = kv0 + 64;
    // issue-early: next chunk's K/V loads overlap this iteration's compute
    if (kv1 < SEQ) {
      rkh = *(const short8_t*)(Kbh + (size_t)(kv1 + srow) * DK + scol);
      rv  = *(const short8_t*)(Vb  + (size_t)srow * SEQ + kv1 + scol);
    }

    // ---- S^T = K_hi (Q_hi + Q_lo)^T : 2 chains, K frags from LDS ----
    f32x4_t sa[4] = {};          // sa[ni]: rows kv=ni*16+g*4+j, col q=c
    __builtin_amdgcn_s_setprio(1);
#pragma unroll
    for (int ks = 0; ks < 2; ++ks) {
#pragma unroll
      for (int ni = 0; ni < 4; ++ni) {
        short8_t ah = *(const short8_t*)(&Khs[(ni * 16 + c) * LSTR + ks * 32 + g * 8]);
        sa[ni] = __builtin_amdgcn_mfma_f32_16x16x32_bf16(
            ah, qfh[ks], sa[ni], 0, 0, 0);
        sa[ni] = __builtin_amdgcn_mfma_f32_16x16x32_bf16(
            ah, qfl[ks], sa[ni], 0, 0, 0);
      }
    }
    __builtin_amdgcn_s_setprio(0);

    // ---- + mask * log2e from prefetched regs; then prefetch t+1 ----
#pragma unroll
    for (int ni = 0; ni < 4; ++ni) {
      sa[ni][0] = fmaf(mpre[ni].x, LOG2E, sa[ni][0]);
      sa[ni][1] = fmaf(mpre[ni].y, LOG2E, sa[ni][1]);
      sa[ni][2] = fmaf(mpre[ni].z, LOG2E, sa[ni][2]);
      sa[ni][3] = fmaf(mpre[ni].w, LOG2E, sa[ni][3]);
    }
    if (kv1 < SEQ) {
#pragma unroll
      for (int ni = 0; ni < 4; ++ni)
        mpre[ni] = *(const float4*)(M0 + kv1 + ni * 16 + g * 4);
    }

    // ---- online softmax (log2 space), defer-max THR=8 ----
    {
      float t = sa[0][0];
#pragma unroll
      for (int ni = 0; ni < 4; ++ni)
#pragma unroll
        for (int j = 0; j < 4; ++j) t = fmaxf(t, sa[ni][j]);
      t = fmaxf(t, __shfl_xor(t, 16));
      t = fmaxf(t, __shfl_xor(t, 32));
      if (!__all(t - mrun <= 8.f)) {
        float mnew = fmaxf(mrun, t);
        float sc = exp2f(mrun - mnew);
        mrun = mnew;
        lrun *= sc;
#pragma unroll
        for (int di = 0; di < 4; ++di)
#pragma unroll
          for (int j = 0; j < 4; ++j) o[di][j] *= sc;
      }
      float psum = 0.f;
#pragma unroll
      for (int ni = 0; ni < 4; ++ni) {
        float p0 = exp2f(sa[ni][0] - mrun);
        float p1 = exp2f(sa[ni][1] - mrun);
        float p2 = exp2f(sa[ni][2] - mrun);
        float p3 = exp2f(sa[ni][3] - mrun);
        psum += (p0 + p1) + (p2 + p3);
        unsigned int u0 = cvt_pk_bf16(p0, p1);
        unsigned int u1 = cvt_pk_bf16(p2, p3);
        unsigned long long pu = ((unsigned long long)u1 << 32) | u0;
        // P store: [q][kv] A-layout, b64, ~2-way max at stride 76
        *(unsigned long long*)(&psw[c * LSTR + ni * 16 + g * 4]) = pu;
      }
      lrun += psum;
    }

    // ---- O^T += V^T P^T : V frags from LDS ----
    __builtin_amdgcn_s_setprio(1);
#pragma unroll
    for (int ks = 0; ks < 2; ++ks) {
      short8_t pb = *(const short8_t*)(&psw[c * LSTR + ks * 32 + g * 8]);
#pragma unroll
      for (int di = 0; di < 4; ++di) {
        short8_t av = *(const short8_t*)(&Vts[(di * 16 + c) * LSTR + ks * 32 + g * 8]);
        o[di] = __builtin_amdgcn_mfma_f32_16x16x32_bf16(
            av, pb, o[di], 0, 0, 0);
      }
    }
    __builtin_amdgcn_s_setprio(0);
  }

  // ---- finalize: reduce l across g-groups, normalize, short4 stores ----
  float s = lrun;
  s += __shfl_xor(s, 16);
  s += __shfl_xor(s, 32);
  float inv = 1.f / s;
  short* Cb = ctx + ((size_t)b * SEQ + qrow0) * DFF + h * DK;
#pragma unroll
  for (int di = 0; di < 4; ++di) {
    short4_t s4;
#pragma unroll
    for (int j = 0; j < 4; ++j)
      s4[j] = (short)f32_to_bf16(o[di][j] * inv);
    *(short4_t*)(Cb + (size_t)c * DFF + di * 16 + g * 4) = s4;
  }
}

// ---------------------------------------------------------------------------
extern "C" void kernel_launch(void* const* d_in, const int* in_sizes, int n_in,
                              void* d_out, int out_size, void* d_ws, size_t ws_size,
                              hipStream_t stream) {
  const float* q    = (const float*)d_in[0];
  const float* k    = (const float*)d_in[1];
  const float* v    = (const float*)d_in[2];
  const float* mask = (const float*)d_in[3];
  const float* Wq   = (const float*)d_in[4];
  const float* Wk   = (const float*)d_in[5];
  const float* Wv   = (const float*)d_in[6];
  const float* Wo   = (const float*)d_in[7];
  float* out = (float*)d_out;

  const size_t NQ = 4194304;   // 4096*1024
  const size_t NW = 1048576;   // 1024*1024
  short* ws   = (short*)d_ws;
  short* qbf  = ws;            // A0; reused as kh_h after Q-proj
  short* kbf  = ws + NQ;       // A1; reused as vtp after K-proj
  short* vbf  = ws + 2 * NQ;   // A2; reused as ctx after V-proj
  short* qh_h = ws + 3 * NQ;
  short* qh_l = ws + 4 * NQ;
  short* wbase = ws + 5 * NQ;  // [wq_h wq_l wk_h wk_l wv_h wv_l wob], NW each
  short* wq_h = wbase;
  short* wq_l = wbase + NW;
  short* wk_h = wbase + 2 * NW;
  short* wk_l = wbase + 3 * NW;
  short* wv_h = wbase + 4 * NW;
  short* wv_l = wbase + 5 * NW;
  short* wob  = wbase + 6 * NW;   // total 5*NQ + 7*NW = 56.6 MB

  short* kh_h = qbf;   // aliases (stream-ordered, safe)
  short* vtp  = kbf;   // V transposed [B,H,64,S]
  short* ctx  = vbf;

  cvt_x_kernel<<<dim3(4096, 3), 256, 0, stream>>>(q, k, v, ws, (int)NQ);
  cvt_w_kernel<<<dim3(1024, 4), 256, 0, stream>>>(Wq, Wk, Wv, Wo, wbase, (int)NW);

  dim3 gg(16, 32);   // N/64, M/128
  gemm_proj<0><<<gg, 256, 0, stream>>>(qbf, wq_h, wq_l, qh_h, qh_l, 4096, 1024);
  gemm_proj<1><<<gg, 256, 0, stream>>>(kbf, wk_h, wk_l, kh_h, nullptr, 4096, 1024);
  gemm_proj<2><<<gg, 256, 0, stream>>>(vbf, wv_h, wv_l, vtp, nullptr, 4096, 1024);

  attn_kernel<<<dim3(32, 16), 512, 0, stream>>>(qh_h, qh_l, kh_h, vtp, mask, ctx);

  gemm_out<<<gg, 256, 0, stream>>>(ctx, wob, out, 4096, 1024);
}